// Round 5
// baseline (298.336 us; speedup 1.0000x reference)
//
#include <hip/hip_runtime.h>
#include <hip/hip_bf16.h>
#include <stdint.h>

// ---------------- problem constants ----------------
#define DIMC  512
#define NHEAD 16
#define HDIM  32
#define NTOK  65536          // 4*128*128 tokens
#define QKVN  1536           // 3*DIMC
static constexpr float SCALE_F = 0.17677669529663687f;  // HD^-0.5

typedef __attribute__((ext_vector_type(4))) float  f32x4;
typedef __attribute__((ext_vector_type(8))) __bf16 bf16x8;

__device__ __forceinline__ uint16_t f2bf(float f) {
  union { float f; uint32_t u; } v; v.f = f;
  return (uint16_t)((v.u + 0x7FFFu + ((v.u >> 16) & 1u)) >> 16);
}

// async global->LDS, 16B/lane; LDS dest is wave-uniform base (+lane*16 by HW)
__device__ __forceinline__ void gload_lds16(const void* g, void* l) {
  __builtin_amdgcn_global_load_lds((const __attribute__((address_space(1))) void*)g,
                                   (__attribute__((address_space(3))) void*)l,
                                   16, 0, 0);
}

// ---------------------------------------------------------------------------
// fp32 -> bf16 convert (vectorized, grid-stride). n4 = element count / 4.
// ---------------------------------------------------------------------------
__global__ void cvt_f32_bf16(const float* __restrict__ src,
                             uint16_t* __restrict__ dst, int n4)
{
  int i = blockIdx.x * blockDim.x + threadIdx.x;
  const int stride = gridDim.x * blockDim.x;
  for (; i < n4; i += stride) {
    const float4 v = ((const float4*)src)[i];
    ushort4 o;
    o.x = f2bf(v.x); o.y = f2bf(v.y); o.z = f2bf(v.z); o.w = f2bf(v.w);
    ((ushort4*)dst)[i] = o;
  }
}

// ---------------------------------------------------------------------------
// 256x256 8-phase GEMM, single barrier/phase, reads hoisted one phase early.
// Register schedule (period 4, tiles alternate slots s0/s1):
//   p%4==0: MFMA(aX,b0) acc[0][0]; read b1 <- slot.B1
//   p%4==1: MFMA(aX,b1) acc[0][1]; read aY <- slot.A1
//   p%4==2: MFMA(aY,b0) acc[1][0]; (no read)
//   p%4==3: MFMA(aY,b1) acc[1][1]; read aX <- next-slot.A0, b0 <- next-slot.B0
// Stage schedule/iter (computing tiles T=t2,T+1): p0:s1.A1<-k1 p1:s1.B1<-k1
//   p2:s0.A0<-k2,vm6 p3:s0.B0<-k2,vm4 p4:s0.A1<-k2 p5:s0.B1<-k2
//   p6:s1.A0<-k3,vm6 p7:s1.B0<-k3,vm4
// vmcnt ledger (in loads; 2 per STAGE; steady-state enter p0 with 4):
//   p2-end 10 -> vm6 completes s1.A0,B0   (guards p3 reads)
//   p3-end  8 -> vm4 completes s1.A1,B1   (guards p4,p5 reads)
//   p6-end 10 -> vm6 completes s0.A0,B0   (guards p7 reads)
//   p7-end  8 -> vm4 completes s0.A1,B1   (guards p0',p1' reads) -> back to 4
// Overwrite safety: every region is re-staged >=2 barriers after its last
// ds_read has been consumed (consumption forced by MFMA data-dep lgkmcnt).
// Swizzle (T2): logical byte o stored at o^((row&7)<<4); staged via
// pre-swizzled GLOBAL source (linear LDS dest), read with the same XOR.
// ---------------------------------------------------------------------------
template <bool OUT_F32>
__global__ __launch_bounds__(512, 2)
void gemm256_8ph(const uint16_t* __restrict__ A,
                 const uint16_t* __restrict__ B,
                 const float* __restrict__ bias,
                 void* __restrict__ Cv,
                 int M, int N, int K, int gx)
{
  __shared__ __align__(16) char lds[131072];

  const int tid = threadIdx.x;
  const int l  = tid & 63, w = tid >> 6;
  const int wm = w >> 2,  wn = w & 3;
  const int lm = l & 15,  lq = l >> 4;

  // T1: bijective XCD swizzle (m204)
  const int nwg = gridDim.x;
  const int qq = nwg >> 3, rr = nwg & 7;
  const int xcd = blockIdx.x & 7, loc = blockIdx.x >> 3;
  const int sw = (xcd < rr ? xcd * (qq + 1) : rr * (qq + 1) + (xcd - rr) * qq) + loc;
  const long m0 = (long)(sw / gx) * 256;
  const long n0 = (long)(sw % gx) * 256;

  // staging source map: row = ld*64 + (tid>>3); col-byte = ((tid&7)^(row&7))<<4
  const int srow  = tid >> 3;
  const int scolb = (((tid & 7) ^ (srow & 7)) << 4);
  const uint16_t* Ags = A + (m0 + srow) * (long)K + (scolb >> 1);
  const uint16_t* Bgs = B + (n0 + srow) * (long)K + (scolb >> 1);
  char* ldsW = lds + (w << 10);

#define STAGE(Gs, regionOff, half, kt)                                        \
  {                                                                           \
    const uint16_t* s0_ = (Gs) + (size_t)((half) * 128) * K + (kt);           \
    gload_lds16(s0_,                  ldsW + (regionOff));                    \
    gload_lds16(s0_ + (size_t)64 * K, ldsW + (regionOff) + 8192);             \
  }

  // fragment-read offsets (swizzled)
  const int colx0 = ((lq ^ (lm & 7)) << 4);
  const int aoff0 = (wm * 64 + lm) * 128 + colx0;
  const int aoff1 = (wm * 64 + lm) * 128 + (colx0 ^ 64);
  const int boff0 = (wn * 32 + lm) * 128 + colx0;
  const int boff1 = (wn * 32 + lm) * 128 + (colx0 ^ 64);

  f32x4  acc[2][2][4][2] = {};
  bf16x8 aX[4][2], aY[4][2];   // A fragment ping-pong sets
  bf16x8 b0[2][2], b1[2][2];   // B fragment sets (qn=0 / qn=1)

#define RD_A(DST, OFF)                                                        \
  _Pragma("unroll") for (int i = 0; i < 4; ++i) {                             \
    DST[i][0] = *(const bf16x8*)(lds + (OFF) + aoff0 + i * 2048);             \
    DST[i][1] = *(const bf16x8*)(lds + (OFF) + aoff1 + i * 2048);             \
  }
#define RD_B(DST, OFF)                                                        \
  _Pragma("unroll") for (int j = 0; j < 2; ++j) {                             \
    DST[j][0] = *(const bf16x8*)(lds + (OFF) + boff0 + j * 2048);             \
    DST[j][1] = *(const bf16x8*)(lds + (OFF) + boff1 + j * 2048);             \
  }
#define MFMA16(AS, BS, QM, QN)                                                \
  __builtin_amdgcn_s_setprio(1);                                              \
  _Pragma("unroll") for (int kk = 0; kk < 2; ++kk)                            \
    _Pragma("unroll") for (int i = 0; i < 4; ++i)                             \
      _Pragma("unroll") for (int j = 0; j < 2; ++j)                           \
        acc[QM][QN][i][j] = __builtin_amdgcn_mfma_f32_16x16x32_bf16(          \
            AS[i][kk], BS[j][kk], acc[QM][QN][i][j], 0, 0, 0);                \
  __builtin_amdgcn_s_setprio(0);
#define VMW(N) asm volatile("s_waitcnt vmcnt(" #N ")" ::: "memory");
#define BAR()  __builtin_amdgcn_s_barrier();

  // LDS region offsets: s0.A0=0 s0.A1=16384 s0.B0=32768 s0.B1=49152; s1 = +65536
  // prologue: stage s0 (tile0, k=0) fully + s1.A0/B0 (tile1, k=64)
  STAGE(Ags, 0,             0, 0)
  STAGE(Bgs, 32768,         0, 0)
  STAGE(Ags, 16384,         1, 0)
  STAGE(Bgs, 49152,         1, 0)
  STAGE(Ags, 65536,         0, 64)
  STAGE(Bgs, 65536 + 32768, 0, 64)
  VMW(8) BAR()                      // s0.A0,B0 landed
  RD_A(aX, 0) RD_B(b0, 32768)       // warm first-phase fragments
  VMW(4) BAR()                      // s0.A1,B1 landed (guards p0,p1 reads)
  // loop entry invariant: 4 loads outstanding (s1.A0,B0)

  for (int t2 = 0; t2 < K / 64; t2 += 2) {
    const int k1 = (t2 + 1) * 64;
    int k2 = (t2 + 2) * 64; if (k2 >= K) k2 = 0;   // clamped: staged, never used
    int k3 = (t2 + 3) * 64; if (k3 >= K) k3 = 0;

    // ---- tile T (slot0) ----
    RD_B(b1, 49152)                 STAGE(Ags, 65536 + 16384, 1, k1)
    MFMA16(aX, b0, 0, 0)            BAR()                          // p0
    RD_A(aY, 16384)                 STAGE(Bgs, 65536 + 49152, 1, k1)
    MFMA16(aX, b1, 0, 1)            BAR()                          // p1
    STAGE(Ags, 0, 0, k2)
    MFMA16(aY, b0, 1, 0)            VMW(6) BAR()                   // p2
    RD_A(aX, 65536) RD_B(b0, 65536 + 32768)
    STAGE(Bgs, 32768, 0, k2)
    MFMA16(aY, b1, 1, 1)            VMW(4) BAR()                   // p3
    // ---- tile T+1 (slot1) ----
    RD_B(b1, 65536 + 49152)         STAGE(Ags, 16384, 1, k2)
    MFMA16(aX, b0, 0, 0)            BAR()                          // p4
    RD_A(aY, 65536 + 16384)         STAGE(Bgs, 49152, 1, k2)
    MFMA16(aX, b1, 0, 1)            BAR()                          // p5
    STAGE(Ags, 65536, 0, k3)
    MFMA16(aY, b0, 1, 0)            VMW(6) BAR()                   // p6
    RD_A(aX, 0) RD_B(b0, 32768)
    STAGE(Bgs, 65536 + 32768, 0, k3)
    MFMA16(aY, b1, 1, 1)            VMW(4) BAR()                   // p7
  }
#undef STAGE
#undef RD_A
#undef RD_B
#undef MFMA16
#undef VMW
#undef BAR

  // epilogue: C/D layout col = l&15, row = (l>>4)*4 + r
#pragma unroll
  for (int qm = 0; qm < 2; ++qm)
#pragma unroll
  for (int qn = 0; qn < 2; ++qn)
#pragma unroll
  for (int i = 0; i < 4; ++i)
#pragma unroll
  for (int j = 0; j < 2; ++j) {
    const long m = m0 + qm * 128 + wm * 64 + i * 16 + lq * 4;
    const long n = n0 + qn * 128 + wn * 32 + j * 16 + lm;
    const float bv = bias[n];
#pragma unroll
    for (int r = 0; r < 4; ++r) {
      const float val = acc[qm][qn][i][j][r] + bv;
      if (OUT_F32) ((float*)Cv)[(m + r) * (long)N + n] = val;
      else         ((uint16_t*)Cv)[(m + r) * (long)N + n] = f2bf(val);
    }
  }
}

// ---------------------------------------------------------------------------
// Windowed dilated attention: one wave per (group g, head h).  (unchanged)
// ---------------------------------------------------------------------------
__global__ void attn_win(const uint16_t* __restrict__ QKV,  // [NTOK][1536] bf16
                         uint16_t* __restrict__ O)          // [NTOK][512]  bf16
{
  __shared__ __align__(16) __bf16 Pl[4][64][72];

  const int tid = threadIdx.x;
  const int l  = tid & 63, w = tid >> 6;
  const int lm = l & 15,  lq = l >> 4;
  const int bid = blockIdx.x;
  const int g = bid >> 2;
  const int h = (bid & 3) * 4 + w;

  const int d1 = g & 1, d0 = (g >> 1) & 1;
  const int wx = (g >> 2) & 7, wy = (g >> 5) & 7, bb = g >> 8;
  const long tbase = ((long)(bb * 128 + wy * 16 + d0) * 128) + wx * 16 + d1;

  f32x4 invs;
#pragma unroll
  for (int i = 0; i < 4; ++i)
    invs[i] = exp2f(-1.6609640474436813f * (float)((lq & 1) * 4 + i));

  const int co_q = h * HDIM;
  const int co_k = DIMC + h * HDIM;
  const int co_v = 2 * DIMC + h * HDIM;

  bf16x8 qf[4], kf[4];
#pragma unroll
  for (int f = 0; f < 4; ++f) {
    const int n  = f * 16 + lm;
    const int iy = n >> 3, ix = n & 7;
    const float pos = (lq < 2) ? (float)iy : (float)ix;
    const long t = tbase + iy * 256 + ix * 2;
    const uint16_t* qp = QKV + t * QKVN + co_q + lq * 8;
    const uint16_t* kp = QKV + t * QKVN + co_k + lq * 8;
    {
      bf16x8 raw = *(const bf16x8*)qp, o;
#pragma unroll
      for (int i = 0; i < 4; ++i) {
        float x1 = (float)raw[2 * i], x2 = (float)raw[2 * i + 1];
        float s, c; __sincosf(pos * invs[i], &s, &c);
        o[2 * i]     = (__bf16)((x1 * c - x2 * s) * SCALE_F);
        o[2 * i + 1] = (__bf16)((x1 * s + x2 * c) * SCALE_F);
      }
      qf[f] = o;
    }
    {
      bf16x8 raw = *(const bf16x8*)kp, o;
#pragma unroll
      for (int i = 0; i < 4; ++i) {
        float x1 = (float)raw[2 * i], x2 = (float)raw[2 * i + 1];
        float s, c; __sincosf(pos * invs[i], &s, &c);
        o[2 * i]     = (__bf16)(x1 * c - x2 * s);
        o[2 * i + 1] = (__bf16)(x1 * s + x2 * c);
      }
      kf[f] = o;
    }
  }

  const f32x4 fzero = {0.f, 0.f, 0.f, 0.f};
  f32x4 s[4][4];
#pragma unroll
  for (int mi = 0; mi < 4; ++mi)
#pragma unroll
    for (int ni = 0; ni < 4; ++ni)
      s[mi][ni] = __builtin_amdgcn_mfma_f32_16x16x32_bf16(qf[mi], kf[ni], fzero, 0, 0, 0);

  float rsum[4][4];
#pragma unroll
  for (int mi = 0; mi < 4; ++mi)
#pragma unroll
    for (int r = 0; r < 4; ++r) {
      float m = s[mi][0][r];
#pragma unroll
      for (int ni = 1; ni < 4; ++ni) m = fmaxf(m, s[mi][ni][r]);
      m = fmaxf(m, __shfl_xor(m, 1));
      m = fmaxf(m, __shfl_xor(m, 2));
      m = fmaxf(m, __shfl_xor(m, 4));
      m = fmaxf(m, __shfl_xor(m, 8));
      float sum = 0.f;
#pragma unroll
      for (int ni = 0; ni < 4; ++ni) {
        float p = expf(s[mi][ni][r] - m);
        s[mi][ni][r] = p;
        sum += p;
      }
      sum += __shfl_xor(sum, 1);
      sum += __shfl_xor(sum, 2);
      sum += __shfl_xor(sum, 4);
      sum += __shfl_xor(sum, 8);
      rsum[mi][r] = sum;
    }

#pragma unroll
  for (int mi = 0; mi < 4; ++mi)
#pragma unroll
    for (int ni = 0; ni < 4; ++ni)
#pragma unroll
      for (int r = 0; r < 4; ++r)
        Pl[w][mi * 16 + lq * 4 + r][ni * 16 + lm] = (__bf16)s[mi][ni][r];

  bf16x8 pa[4][2];
#pragma unroll
  for (int mi = 0; mi < 4; ++mi)
#pragma unroll
    for (int kk = 0; kk < 2; ++kk)
      pa[mi][kk] = *(const bf16x8*)(&Pl[w][mi * 16 + lm][kk * 32 + lq * 8]);

  bf16x8 vf[2][2];
#pragma unroll
  for (int kk = 0; kk < 2; ++kk)
#pragma unroll
    for (int n2 = 0; n2 < 2; ++n2) {
      const int nb = kk * 32 + lq * 8;
      const long tb2 = tbase + (long)(nb >> 3) * 256;
      const uint16_t* vp = QKV + co_v + n2 * 16 + lm;
      bf16x8 o;
#pragma unroll
      for (int i = 0; i < 8; ++i)
        o[i] = *(const __bf16*)(vp + (tb2 + 2 * i) * QKVN);
      vf[kk][n2] = o;
    }

  f32x4 oacc[4][2] = {};
#pragma unroll
  for (int kk = 0; kk < 2; ++kk)
#pragma unroll
    for (int mi = 0; mi < 4; ++mi)
#pragma unroll
      for (int n2 = 0; n2 < 2; ++n2)
        oacc[mi][n2] = __builtin_amdgcn_mfma_f32_16x16x32_bf16(
            pa[mi][kk], vf[kk][n2], oacc[mi][n2], 0, 0, 0);

#pragma unroll
  for (int mi = 0; mi < 4; ++mi)
#pragma unroll
    for (int r = 0; r < 4; ++r) {
      const int n = mi * 16 + lq * 4 + r;
      const long t = tbase + (n >> 3) * 256 + (n & 7) * 2;
      const float rinv = 1.0f / rsum[mi][r];
#pragma unroll
      for (int n2 = 0; n2 < 2; ++n2)
        O[t * DIMC + h * HDIM + n2 * 16 + lm] = f2bf(oacc[mi][n2][r] * rinv);
    }
}

// ---------------------------------------------------------------------------
extern "C" void kernel_launch(void* const* d_in, const int* in_sizes, int n_in,
                              void* d_out, int out_size, void* d_ws, size_t ws_size,
                              hipStream_t stream)
{
  const float* x      = (const float*)d_in[0];   // [65536][512] fp32
  const float* qkv_w  = (const float*)d_in[1];   // [1536][512]  fp32
  const float* qkv_b  = (const float*)d_in[2];   // [1536]       fp32
  const float* proj_w = (const float*)d_in[3];   // [512][512]   fp32
  const float* proj_b = (const float*)d_in[4];   // [512]        fp32
  float* out = (float*)d_out;                    // [65536][512] fp32

  uint16_t* xb    = (uint16_t*)d_ws;                     // 64 MiB
  uint16_t* qwb   = xb    + (size_t)NTOK * DIMC;         // 1.5 MiB
  uint16_t* pwb   = qwb   + (size_t)QKVN * DIMC;         // 0.5 MiB
  uint16_t* qkv   = pwb   + (size_t)DIMC * DIMC;         // 192 MiB
  uint16_t* attn  = qkv   + (size_t)NTOK * QKVN;         // 64 MiB

  // 0) fp32 -> bf16 conversions
  cvt_f32_bf16<<<2048, 256, 0, stream>>>(x,      xb,  NTOK * DIMC / 4);
  cvt_f32_bf16<<<512,  256, 0, stream>>>(qkv_w,  qwb, QKVN * DIMC / 4);
  cvt_f32_bf16<<<256,  256, 0, stream>>>(proj_w, pwb, DIMC * DIMC / 4);

  // 1) QKV = x @ qkv_w^T + qkv_b   (bf16 out)
  gemm256_8ph<false><<<dim3((NTOK / 256) * (QKVN / 256)), dim3(512), 0, stream>>>(
      xb, qwb, qkv_b, qkv, NTOK, QKVN, DIMC, QKVN / 256);

  // 2) windowed dilated attention with fused RoPE (1024 groups x 16 heads)
  attn_win<<<dim3(1024 * 4), dim3(256), 0, stream>>>(qkv, attn);

  // 3) out = attn @ proj_w^T + proj_b   (fp32 out)
  gemm256_8ph<true><<<dim3((NTOK / 256) * (DIMC / 256)), dim3(512), 0, stream>>>(
      attn, pwb, proj_b, out, NTOK, DIMC, DIMC, DIMC / 256);
}

// Round 6
// 292.743 us; speedup vs baseline: 1.0191x; 1.0191x over previous
//
#include <hip/hip_runtime.h>
#include <hip/hip_bf16.h>
#include <stdint.h>

// ---------------- problem constants ----------------
#define DIMC  512
#define NHEAD 16
#define HDIM  32
#define NTOK  65536          // 4*128*128 tokens
#define QKVN  1536           // 3*DIMC
static constexpr float SCALE_F = 0.17677669529663687f;  // HD^-0.5

typedef __attribute__((ext_vector_type(4))) float  f32x4;
typedef __attribute__((ext_vector_type(8))) __bf16 bf16x8;

__device__ __forceinline__ uint16_t f2bf(float f) {
  union { float f; uint32_t u; } v; v.f = f;
  return (uint16_t)((v.u + 0x7FFFu + ((v.u >> 16) & 1u)) >> 16);
}

// async global->LDS, 16B/lane; LDS dest is wave-uniform base (+lane*16 by HW)
__device__ __forceinline__ void gload_lds16(const void* g, void* l) {
  __builtin_amdgcn_global_load_lds((const __attribute__((address_space(1))) void*)g,
                                   (__attribute__((address_space(3))) void*)l,
                                   16, 0, 0);
}

// ---------------------------------------------------------------------------
// fp32 -> bf16 convert (vectorized, grid-stride). n4 = element count / 4.
// ---------------------------------------------------------------------------
__global__ void cvt_f32_bf16(const float* __restrict__ src,
                             uint16_t* __restrict__ dst, int n4)
{
  int i = blockIdx.x * blockDim.x + threadIdx.x;
  const int stride = gridDim.x * blockDim.x;
  for (; i < n4; i += stride) {
    const float4 v = ((const float4*)src)[i];
    ushort4 o;
    o.x = f2bf(v.x); o.y = f2bf(v.y); o.z = f2bf(v.z); o.w = f2bf(v.w);
    ((ushort4*)dst)[i] = o;
  }
}

// ---------------------------------------------------------------------------
// 256x256 8-phase GEMM, single RAW-ASM barrier per phase (test: does the
// barrier builtin emit an implicit vmcnt(0) drain? raw "s_barrier" cannot).
// Schedule identical to round 5 (ledger re-verified):
//   p%4==0: MFMA(aX,b0); read b1       p%4==1: MFMA(aX,b1); read aY
//   p%4==2: MFMA(aY,b0)                p%4==3: MFMA(aY,b1); read aX',b0'
// Stages/iter: p0:s1.A1 p1:s1.B1 p2:s0.A0,vm6 p3:s0.B0,vm4 p4:s0.A1 p5:s0.B1
//   p6:s1.A0,vm6 p7:s1.B0,vm4
// Per-wave vmcnt completes THIS wave's DMA slice before its barrier; the
// barrier then publishes all 8 waves' slices (vmcnt is per-wave: this
// ordering is the only correct one). All regions: last-read -> re-stage
// gap >= 2 barriers. Swizzle: byte o stored at o^((row&7)<<4), staged via
// pre-swizzled global source (linear LDS dest), read with the same XOR.
// ---------------------------------------------------------------------------
template <bool OUT_F32>
__global__ __launch_bounds__(512, 2)
void gemm256_8ph(const uint16_t* __restrict__ A,
                 const uint16_t* __restrict__ B,
                 const float* __restrict__ bias,
                 void* __restrict__ Cv,
                 int M, int N, int K, int gx)
{
  __shared__ __align__(16) char lds[131072];

  const int tid = threadIdx.x;
  const int l  = tid & 63, w = tid >> 6;
  const int wm = w >> 2,  wn = w & 3;
  const int lm = l & 15,  lq = l >> 4;

  // T1: bijective XCD swizzle (m204)
  const int nwg = gridDim.x;
  const int qq = nwg >> 3, rr = nwg & 7;
  const int xcd = blockIdx.x & 7, loc = blockIdx.x >> 3;
  const int sw = (xcd < rr ? xcd * (qq + 1) : rr * (qq + 1) + (xcd - rr) * qq) + loc;
  const long m0 = (long)(sw / gx) * 256;
  const long n0 = (long)(sw % gx) * 256;

  // staging source map: row = ld*64 + (tid>>3); col-byte = ((tid&7)^(row&7))<<4
  const int srow  = tid >> 3;
  const int scolb = (((tid & 7) ^ (srow & 7)) << 4);
  const uint16_t* Ags = A + (m0 + srow) * (long)K + (scolb >> 1);
  const uint16_t* Bgs = B + (n0 + srow) * (long)K + (scolb >> 1);
  char* ldsW = lds + (w << 10);

#define STAGE(Gs, regionOff, half, kt)                                        \
  {                                                                           \
    const uint16_t* s0_ = (Gs) + (size_t)((half) * 128) * K + (kt);           \
    gload_lds16(s0_,                  ldsW + (regionOff));                    \
    gload_lds16(s0_ + (size_t)64 * K, ldsW + (regionOff) + 8192);             \
  }

  // fragment-read offsets (swizzled)
  const int colx0 = ((lq ^ (lm & 7)) << 4);
  const int aoff0 = (wm * 64 + lm) * 128 + colx0;
  const int aoff1 = (wm * 64 + lm) * 128 + (colx0 ^ 64);
  const int boff0 = (wn * 32 + lm) * 128 + colx0;
  const int boff1 = (wn * 32 + lm) * 128 + (colx0 ^ 64);

  f32x4  acc[2][2][4][2] = {};
  bf16x8 aX[4][2], aY[4][2];   // A fragment ping-pong sets
  bf16x8 b0[2][2], b1[2][2];   // B fragment sets (qn=0 / qn=1)

#define RD_A(DST, OFF)                                                        \
  _Pragma("unroll") for (int i = 0; i < 4; ++i) {                             \
    DST[i][0] = *(const bf16x8*)(lds + (OFF) + aoff0 + i * 2048);             \
    DST[i][1] = *(const bf16x8*)(lds + (OFF) + aoff1 + i * 2048);             \
  }
#define RD_B(DST, OFF)                                                        \
  _Pragma("unroll") for (int j = 0; j < 2; ++j) {                             \
    DST[j][0] = *(const bf16x8*)(lds + (OFF) + boff0 + j * 2048);             \
    DST[j][1] = *(const bf16x8*)(lds + (OFF) + boff1 + j * 2048);             \
  }
#define MFMA16(AS, BS, QM, QN)                                                \
  __builtin_amdgcn_s_setprio(1);                                              \
  _Pragma("unroll") for (int kk = 0; kk < 2; ++kk)                            \
    _Pragma("unroll") for (int i = 0; i < 4; ++i)                             \
      _Pragma("unroll") for (int j = 0; j < 2; ++j)                           \
        acc[QM][QN][i][j] = __builtin_amdgcn_mfma_f32_16x16x32_bf16(          \
            AS[i][kk], BS[j][kk], acc[QM][QN][i][j], 0, 0, 0);                \
  __builtin_amdgcn_s_setprio(0);
#define VMW(N) asm volatile("s_waitcnt vmcnt(" #N ")" ::: "memory");
#define BAR()  asm volatile("s_barrier" ::: "memory");

  // LDS region offsets: s0.A0=0 s0.A1=16384 s0.B0=32768 s0.B1=49152; s1 = +65536
  // prologue: stage s0 (tile0, k=0) fully + s1.A0/B0 (tile1, k=64)
  STAGE(Ags, 0,             0, 0)
  STAGE(Bgs, 32768,         0, 0)
  STAGE(Ags, 16384,         1, 0)
  STAGE(Bgs, 49152,         1, 0)
  STAGE(Ags, 65536,         0, 64)
  STAGE(Bgs, 65536 + 32768, 0, 64)
  VMW(8) BAR()                      // s0.A0,B0 landed (own-wave), published
  RD_A(aX, 0) RD_B(b0, 32768)       // warm first-phase fragments
  VMW(4) BAR()                      // s0.A1,B1 landed (guards p0,p1 reads)
  // loop entry invariant: 4 loads outstanding (s1.A0,B0)

  for (int t2 = 0; t2 < K / 64; t2 += 2) {
    const int k1 = (t2 + 1) * 64;
    int k2 = (t2 + 2) * 64; if (k2 >= K) k2 = 0;   // clamped: staged, never used
    int k3 = (t2 + 3) * 64; if (k3 >= K) k3 = 0;

    // ---- tile T (slot0) ----
    RD_B(b1, 49152)                 STAGE(Ags, 65536 + 16384, 1, k1)
    MFMA16(aX, b0, 0, 0)            BAR()                          // p0
    RD_A(aY, 16384)                 STAGE(Bgs, 65536 + 49152, 1, k1)
    MFMA16(aX, b1, 0, 1)            BAR()                          // p1
    STAGE(Ags, 0, 0, k2)
    MFMA16(aY, b0, 1, 0)            VMW(6) BAR()                   // p2
    RD_A(aX, 65536) RD_B(b0, 65536 + 32768)
    STAGE(Bgs, 32768, 0, k2)
    MFMA16(aY, b1, 1, 1)            VMW(4) BAR()                   // p3
    // ---- tile T+1 (slot1) ----
    RD_B(b1, 65536 + 49152)         STAGE(Ags, 16384, 1, k2)
    MFMA16(aX, b0, 0, 0)            BAR()                          // p4
    RD_A(aY, 65536 + 16384)         STAGE(Bgs, 49152, 1, k2)
    MFMA16(aX, b1, 0, 1)            BAR()                          // p5
    STAGE(Ags, 65536, 0, k3)
    MFMA16(aY, b0, 1, 0)            VMW(6) BAR()                   // p6
    RD_A(aX, 0) RD_B(b0, 32768)
    STAGE(Bgs, 65536 + 32768, 0, k3)
    MFMA16(aY, b1, 1, 1)            VMW(4) BAR()                   // p7
  }
#undef STAGE
#undef RD_A
#undef RD_B
#undef MFMA16
#undef VMW
#undef BAR

  // epilogue: C/D layout col = l&15, row = (l>>4)*4 + r
#pragma unroll
  for (int qm = 0; qm < 2; ++qm)
#pragma unroll
  for (int qn = 0; qn < 2; ++qn)
#pragma unroll
  for (int i = 0; i < 4; ++i)
#pragma unroll
  for (int j = 0; j < 2; ++j) {
    const long m = m0 + qm * 128 + wm * 64 + i * 16 + lq * 4;
    const long n = n0 + qn * 128 + wn * 32 + j * 16 + lm;
    const float bv = bias[n];
#pragma unroll
    for (int r = 0; r < 4; ++r) {
      const float val = acc[qm][qn][i][j][r] + bv;
      if (OUT_F32) ((float*)Cv)[(m + r) * (long)N + n] = val;
      else         ((uint16_t*)Cv)[(m + r) * (long)N + n] = f2bf(val);
    }
  }
}

// ---------------------------------------------------------------------------
// Windowed dilated attention: one wave per (group g, head h).  (unchanged)
// ---------------------------------------------------------------------------
__global__ void attn_win(const uint16_t* __restrict__ QKV,  // [NTOK][1536] bf16
                         uint16_t* __restrict__ O)          // [NTOK][512]  bf16
{
  __shared__ __align__(16) __bf16 Pl[4][64][72];

  const int tid = threadIdx.x;
  const int l  = tid & 63, w = tid >> 6;
  const int lm = l & 15,  lq = l >> 4;
  const int bid = blockIdx.x;
  const int g = bid >> 2;
  const int h = (bid & 3) * 4 + w;

  const int d1 = g & 1, d0 = (g >> 1) & 1;
  const int wx = (g >> 2) & 7, wy = (g >> 5) & 7, bb = g >> 8;
  const long tbase = ((long)(bb * 128 + wy * 16 + d0) * 128) + wx * 16 + d1;

  f32x4 invs;
#pragma unroll
  for (int i = 0; i < 4; ++i)
    invs[i] = exp2f(-1.6609640474436813f * (float)((lq & 1) * 4 + i));

  const int co_q = h * HDIM;
  const int co_k = DIMC + h * HDIM;
  const int co_v = 2 * DIMC + h * HDIM;

  bf16x8 qf[4], kf[4];
#pragma unroll
  for (int f = 0; f < 4; ++f) {
    const int n  = f * 16 + lm;
    const int iy = n >> 3, ix = n & 7;
    const float pos = (lq < 2) ? (float)iy : (float)ix;
    const long t = tbase + iy * 256 + ix * 2;
    const uint16_t* qp = QKV + t * QKVN + co_q + lq * 8;
    const uint16_t* kp = QKV + t * QKVN + co_k + lq * 8;
    {
      bf16x8 raw = *(const bf16x8*)qp, o;
#pragma unroll
      for (int i = 0; i < 4; ++i) {
        float x1 = (float)raw[2 * i], x2 = (float)raw[2 * i + 1];
        float s, c; __sincosf(pos * invs[i], &s, &c);
        o[2 * i]     = (__bf16)((x1 * c - x2 * s) * SCALE_F);
        o[2 * i + 1] = (__bf16)((x1 * s + x2 * c) * SCALE_F);
      }
      qf[f] = o;
    }
    {
      bf16x8 raw = *(const bf16x8*)kp, o;
#pragma unroll
      for (int i = 0; i < 4; ++i) {
        float x1 = (float)raw[2 * i], x2 = (float)raw[2 * i + 1];
        float s, c; __sincosf(pos * invs[i], &s, &c);
        o[2 * i]     = (__bf16)(x1 * c - x2 * s);
        o[2 * i + 1] = (__bf16)(x1 * s + x2 * c);
      }
      kf[f] = o;
    }
  }

  const f32x4 fzero = {0.f, 0.f, 0.f, 0.f};
  f32x4 s[4][4];
#pragma unroll
  for (int mi = 0; mi < 4; ++mi)
#pragma unroll
    for (int ni = 0; ni < 4; ++ni)
      s[mi][ni] = __builtin_amdgcn_mfma_f32_16x16x32_bf16(qf[mi], kf[ni], fzero, 0, 0, 0);

  float rsum[4][4];
#pragma unroll
  for (int mi = 0; mi < 4; ++mi)
#pragma unroll
    for (int r = 0; r < 4; ++r) {
      float m = s[mi][0][r];
#pragma unroll
      for (int ni = 1; ni < 4; ++ni) m = fmaxf(m, s[mi][ni][r]);
      m = fmaxf(m, __shfl_xor(m, 1));
      m = fmaxf(m, __shfl_xor(m, 2));
      m = fmaxf(m, __shfl_xor(m, 4));
      m = fmaxf(m, __shfl_xor(m, 8));
      float sum = 0.f;
#pragma unroll
      for (int ni = 0; ni < 4; ++ni) {
        float p = expf(s[mi][ni][r] - m);
        s[mi][ni][r] = p;
        sum += p;
      }
      sum += __shfl_xor(sum, 1);
      sum += __shfl_xor(sum, 2);
      sum += __shfl_xor(sum, 4);
      sum += __shfl_xor(sum, 8);
      rsum[mi][r] = sum;
    }

#pragma unroll
  for (int mi = 0; mi < 4; ++mi)
#pragma unroll
    for (int ni = 0; ni < 4; ++ni)
#pragma unroll
      for (int r = 0; r < 4; ++r)
        Pl[w][mi * 16 + lq * 4 + r][ni * 16 + lm] = (__bf16)s[mi][ni][r];

  bf16x8 pa[4][2];
#pragma unroll
  for (int mi = 0; mi < 4; ++mi)
#pragma unroll
    for (int kk = 0; kk < 2; ++kk)
      pa[mi][kk] = *(const bf16x8*)(&Pl[w][mi * 16 + lm][kk * 32 + lq * 8]);

  bf16x8 vf[2][2];
#pragma unroll
  for (int kk = 0; kk < 2; ++kk)
#pragma unroll
    for (int n2 = 0; n2 < 2; ++n2) {
      const int nb = kk * 32 + lq * 8;
      const long tb2 = tbase + (long)(nb >> 3) * 256;
      const uint16_t* vp = QKV + co_v + n2 * 16 + lm;
      bf16x8 o;
#pragma unroll
      for (int i = 0; i < 8; ++i)
        o[i] = *(const __bf16*)(vp + (tb2 + 2 * i) * QKVN);
      vf[kk][n2] = o;
    }

  f32x4 oacc[4][2] = {};
#pragma unroll
  for (int kk = 0; kk < 2; ++kk)
#pragma unroll
    for (int mi = 0; mi < 4; ++mi)
#pragma unroll
      for (int n2 = 0; n2 < 2; ++n2)
        oacc[mi][n2] = __builtin_amdgcn_mfma_f32_16x16x32_bf16(
            pa[mi][kk], vf[kk][n2], oacc[mi][n2], 0, 0, 0);

#pragma unroll
  for (int mi = 0; mi < 4; ++mi)
#pragma unroll
    for (int r = 0; r < 4; ++r) {
      const int n = mi * 16 + lq * 4 + r;
      const long t = tbase + (n >> 3) * 256 + (n & 7) * 2;
      const float rinv = 1.0f / rsum[mi][r];
#pragma unroll
      for (int n2 = 0; n2 < 2; ++n2)
        O[t * DIMC + h * HDIM + n2 * 16 + lm] = f2bf(oacc[mi][n2][r] * rinv);
    }
}

// ---------------------------------------------------------------------------
extern "C" void kernel_launch(void* const* d_in, const int* in_sizes, int n_in,
                              void* d_out, int out_size, void* d_ws, size_t ws_size,
                              hipStream_t stream)
{
  const float* x      = (const float*)d_in[0];   // [65536][512] fp32
  const float* qkv_w  = (const float*)d_in[1];   // [1536][512]  fp32
  const float* qkv_b  = (const float*)d_in[2];   // [1536]       fp32
  const float* proj_w = (const float*)d_in[3];   // [512][512]   fp32
  const float* proj_b = (const float*)d_in[4];   // [512]        fp32
  float* out = (float*)d_out;                    // [65536][512] fp32

  uint16_t* xb    = (uint16_t*)d_ws;                     // 64 MiB
  uint16_t* qwb   = xb    + (size_t)NTOK * DIMC;         // 1.5 MiB
  uint16_t* pwb   = qwb   + (size_t)QKVN * DIMC;         // 0.5 MiB
  uint16_t* qkv   = pwb   + (size_t)DIMC * DIMC;         // 192 MiB
  uint16_t* attn  = qkv   + (size_t)NTOK * QKVN;         // 64 MiB

  // 0) fp32 -> bf16 conversions
  cvt_f32_bf16<<<2048, 256, 0, stream>>>(x,      xb,  NTOK * DIMC / 4);
  cvt_f32_bf16<<<512,  256, 0, stream>>>(qkv_w,  qwb, QKVN * DIMC / 4);
  cvt_f32_bf16<<<256,  256, 0, stream>>>(proj_w, pwb, DIMC * DIMC / 4);

  // 1) QKV = x @ qkv_w^T + qkv_b   (bf16 out)
  gemm256_8ph<false><<<dim3((NTOK / 256) * (QKVN / 256)), dim3(512), 0, stream>>>(
      xb, qwb, qkv_b, qkv, NTOK, QKVN, DIMC, QKVN / 256);

  // 2) windowed dilated attention with fused RoPE (1024 groups x 16 heads)
  attn_win<<<dim3(1024 * 4), dim3(256), 0, stream>>>(qkv, attn);

  // 3) out = attn @ proj_w^T + proj_b   (fp32 out)
  gemm256_8ph<true><<<dim3((NTOK / 256) * (DIMC / 256)), dim3(512), 0, stream>>>(
      attn, pwb, proj_b, out, NTOK, DIMC, DIMC, DIMC / 256);
}